// Round 10
// baseline (359.331 us; speedup 1.0000x reference)
//
#include <hip/hip_runtime.h>

#define PRO_NUM 64
#define TERM_NUM 512
#define MAX_LEN 1024
#define HID 256

typedef _Float16 f16x8 __attribute__((ext_vector_type(8)));
typedef _Float16 f16x4 __attribute__((ext_vector_type(4)));
typedef float f32x4 __attribute__((ext_vector_type(4)));

__device__ __forceinline__ f16x8 cvt8(const float* __restrict__ s) {
  float4 a = *(const float4*)s;
  float4 b = *(const float4*)(s + 4);
  f16x8 r = {(_Float16)a.x, (_Float16)a.y, (_Float16)a.z, (_Float16)a.w,
             (_Float16)b.x, (_Float16)b.y, (_Float16)b.z, (_Float16)b.w};
  return r;
}

// K1: pro f32 -> fragP + fragT (fragment-ordered f16). Block = (p, 64-l chunk).
__global__ __launch_bounds__(256) void k_prep(const float* __restrict__ pro,
                                              f16x8* __restrict__ fragP,
                                              f16x8* __restrict__ fragT) {
  __shared__ _Float16 ldsA[64][264];
  const int p = blockIdx.y;
  const int lc = blockIdx.x;
  const int tid = threadIdx.x;

  const float* src = pro + ((size_t)p * MAX_LEN + lc * 64) * HID;
  #pragma unroll
  for (int j = 0; j < 16; ++j) {
    int idx = j * 1024 + tid * 4;
    int l = idx >> 8, h = idx & 255;
    float4 v = *(const float4*)(src + idx);
    ldsA[l][h + 0] = (_Float16)v.x;
    ldsA[l][h + 1] = (_Float16)v.y;
    ldsA[l][h + 2] = (_Float16)v.z;
    ldsA[l][h + 3] = (_Float16)v.w;
  }
  __syncthreads();

  const int w = tid >> 6;
  const int lane = tid & 63;
  const int lr = lane & 15;
  const int lg = lane >> 4;

  {
    const int T = lc * 4 + w;
    f16x8* dst = fragP + ((size_t)(p * 64 + T) * 8) * 64 + lane;
    #pragma unroll
    for (int kk = 0; kk < 8; ++kk)
      dst[kk * 64] = *(const f16x8*)&ldsA[w * 16 + lr][kk * 32 + lg * 8];
  }
  #pragma unroll
  for (int hh = 0; hh < 4; ++hh) {
    const int H = w * 4 + hh;
    #pragma unroll
    for (int k2 = 0; k2 < 2; ++k2) {
      const int kc = lc * 2 + k2;
      const int lloc = k2 * 32 + lg * 8;
      f16x8 v;
      #pragma unroll
      for (int i = 0; i < 8; ++i) v[i] = ldsA[lloc + i][H * 16 + lr];
      fragT[((size_t)(p * 16 + H) * 32 + kc) * 64 + lane] = v;
    }
  }
}

// K2 ablation template.
// MODE 0: full (A: QK^T, B: softmax, C: full attn store)  -- the real kernel
// MODE 1: A only (live-sum store, 1 float/thread)
// MODE 2: A + B (live-sum store)
// MODE 3: B + full store, acc seeded without loads
template <int MODE>
__global__ __launch_bounds__(256) void k_qk_t(
    const float* __restrict__ term, const f16x8* __restrict__ fragP,
    const int* __restrict__ lens, float* __restrict__ attn) {
  constexpr bool DO_A = (MODE == 0 || MODE == 1 || MODE == 2);
  constexpr bool DO_B = (MODE == 0 || MODE == 2 || MODE == 3);
  constexpr bool DO_ST = (MODE == 0 || MODE == 3);

  __shared__ float rmx[4][32];
  __shared__ float rsm[4][32];

  const int bid = blockIdx.x;
  const int swz = (bid & 7) * 128 + (bid >> 3);
  const int p = swz >> 4;
  const int t0 = (swz & 15) * 32;

  const int tid = threadIdx.x;
  const int w = tid >> 6;
  const int lane = tid & 63;
  const int lr = lane & 15;
  const int lg = lane >> 4;
  const int len = lens[p];
  const int l0w = w * 256;

  f32x4 acc[2][16];

  if constexpr (DO_A) {
    #pragma unroll
    for (int mt = 0; mt < 2; ++mt)
      #pragma unroll
      for (int i = 0; i < 16; ++i) acc[mt][i] = (f32x4){0.f, 0.f, 0.f, 0.f};

    const float* trow0 = term + (size_t)(t0 + lr) * HID + lg * 8;
    const f16x8* pbw = fragP + ((size_t)(p * 64 + w * 16) * 8) * 64 + lane;

    #pragma unroll
    for (int kk = 0; kk < 8; ++kk) {
      f16x8 a0 = cvt8(trow0 + kk * 32);
      f16x8 a1 = cvt8(trow0 + (size_t)16 * HID + kk * 32);
      f16x8 bf[16];
      #pragma unroll
      for (int tile = 0; tile < 16; ++tile) bf[tile] = pbw[(tile * 8 + kk) * 64];
      #pragma unroll
      for (int tile = 0; tile < 16; ++tile) {
        acc[0][tile] = __builtin_amdgcn_mfma_f32_16x16x32_f16(a0, bf[tile], acc[0][tile], 0, 0, 0);
        acc[1][tile] = __builtin_amdgcn_mfma_f32_16x16x32_f16(a1, bf[tile], acc[1][tile], 0, 0, 0);
      }
    }
  } else {
    // seed acc cheaply (no loads) for MODE 3
    #pragma unroll
    for (int mt = 0; mt < 2; ++mt)
      #pragma unroll
      for (int tile = 0; tile < 16; ++tile)
        #pragma unroll
        for (int r = 0; r < 4; ++r)
          acc[mt][tile][r] = (float)((lane * 7 + tile * 13 + mt * 3 + r) & 31) * 0.03f;
  }

  float inv[2][4] = {{1.f, 1.f, 1.f, 1.f}, {1.f, 1.f, 1.f, 1.f}};

  if constexpr (DO_B) {
    float rmax[2][4];
    #pragma unroll
    for (int mt = 0; mt < 2; ++mt)
      #pragma unroll
      for (int r = 0; r < 4; ++r) rmax[mt][r] = -INFINITY;

    #pragma unroll
    for (int tile = 0; tile < 16; ++tile) {
      int l = l0w + tile * 16 + lr;
      #pragma unroll
      for (int mt = 0; mt < 2; ++mt) {
        #pragma unroll
        for (int r = 0; r < 4; ++r) {
          float s = (l < len) ? acc[mt][tile][r] : -INFINITY;
          acc[mt][tile][r] = s;
          rmax[mt][r] = fmaxf(rmax[mt][r], s);
        }
      }
    }
    #pragma unroll
    for (int m = 1; m < 16; m <<= 1) {
      #pragma unroll
      for (int mt = 0; mt < 2; ++mt)
        #pragma unroll
        for (int r = 0; r < 4; ++r) rmax[mt][r] = fmaxf(rmax[mt][r], __shfl_xor(rmax[mt][r], m));
    }
    if (lr == 0) {
      #pragma unroll
      for (int mt = 0; mt < 2; ++mt)
        #pragma unroll
        for (int r = 0; r < 4; ++r) rmx[w][mt * 16 + lg * 4 + r] = rmax[mt][r];
    }
    __syncthreads();
    float fm[2][4];
    #pragma unroll
    for (int mt = 0; mt < 2; ++mt)
      #pragma unroll
      for (int r = 0; r < 4; ++r) {
        int row = mt * 16 + lg * 4 + r;
        fm[mt][r] = fmaxf(fmaxf(rmx[0][row], rmx[1][row]), fmaxf(rmx[2][row], rmx[3][row]));
      }

    float rsum[2][4] = {{0.f, 0.f, 0.f, 0.f}, {0.f, 0.f, 0.f, 0.f}};
    #pragma unroll
    for (int tile = 0; tile < 16; ++tile) {
      #pragma unroll
      for (int mt = 0; mt < 2; ++mt) {
        #pragma unroll
        for (int r = 0; r < 4; ++r) {
          float e = __expf(acc[mt][tile][r] - fm[mt][r]);
          acc[mt][tile][r] = e;
          rsum[mt][r] += e;
        }
      }
    }
    #pragma unroll
    for (int m = 1; m < 16; m <<= 1) {
      #pragma unroll
      for (int mt = 0; mt < 2; ++mt)
        #pragma unroll
        for (int r = 0; r < 4; ++r) rsum[mt][r] += __shfl_xor(rsum[mt][r], m);
    }
    if (lr == 0) {
      #pragma unroll
      for (int mt = 0; mt < 2; ++mt)
        #pragma unroll
        for (int r = 0; r < 4; ++r) rsm[w][mt * 16 + lg * 4 + r] = rsum[mt][r];
    }
    __syncthreads();
    #pragma unroll
    for (int mt = 0; mt < 2; ++mt)
      #pragma unroll
      for (int r = 0; r < 4; ++r) {
        int row = mt * 16 + lg * 4 + r;
        inv[mt][r] = 1.0f / (rsm[0][row] + rsm[1][row] + rsm[2][row] + rsm[3][row]);
      }
  }

  if constexpr (DO_ST) {
    #pragma unroll
    for (int mt = 0; mt < 2; ++mt) {
      #pragma unroll
      for (int r = 0; r < 4; ++r) {
        const int row = mt * 16 + lg * 4 + r;
        float* arow = attn + ((size_t)(p * TERM_NUM + t0 + row)) * MAX_LEN + l0w + lr;
        #pragma unroll
        for (int tile = 0; tile < 16; ++tile) {
          __builtin_nontemporal_store(acc[mt][tile][r] * inv[mt][r], &arow[tile * 16]);
        }
      }
    }
  } else {
    // keep everything live with a single store per thread
    float s = 0.f;
    #pragma unroll
    for (int mt = 0; mt < 2; ++mt)
      #pragma unroll
      for (int tile = 0; tile < 16; ++tile)
        #pragma unroll
        for (int r = 0; r < 4; ++r) s += acc[mt][tile][r] * inv[mt][r];
    __builtin_nontemporal_store(s, &attn[(size_t)bid * 256 + tid]);
  }
}

// K3: out[p] = attn[p] @ pro[p]. A from attn f32 (L3), B from coalesced fragT.
__global__ __launch_bounds__(256) void k_pv(
    const float* __restrict__ attn, const f16x8* __restrict__ fragT,
    const int* __restrict__ lens, float* __restrict__ out) {
  const int bid = blockIdx.x;
  const int swz = (bid & 7) * 128 + (bid >> 3);
  const int p = swz >> 4;
  const int t0 = (swz & 15) * 32;

  const int tid = threadIdx.x;
  const int w = tid >> 6;
  const int lane = tid & 63;
  const int lr = lane & 15;
  const int lg = lane >> 4;
  const int len = lens[p];

  f32x4 acc2[2][4];
  #pragma unroll
  for (int mt = 0; mt < 2; ++mt)
    #pragma unroll
    for (int nt = 0; nt < 4; ++nt) acc2[mt][nt] = (f32x4){0.f, 0.f, 0.f, 0.f};

  const float* arow0 = attn + ((size_t)(p * TERM_NUM + t0 + lr)) * MAX_LEN + lg * 8;
  const float* arow1 = arow0 + (size_t)16 * MAX_LEN;
  const f16x8* btw = fragT + ((size_t)(p * 16 + w * 4) * 32) * 64 + lane;

  const int ngroups = (((len + 31) >> 5) + 7) >> 3;

  for (int g = 0; g < ngroups; ++g) {
    #pragma unroll
    for (int u = 0; u < 8; ++u) {
      const int kc = g * 8 + u;
      const int k0 = kc * 32;
      f16x8 bf[4];
      #pragma unroll
      for (int nt = 0; nt < 4; ++nt) bf[nt] = btw[(nt * 32 + kc) * 64];
      f16x8 a0 = cvt8(arow0 + k0);
      f16x8 a1 = cvt8(arow1 + k0);
      #pragma unroll
      for (int nt = 0; nt < 4; ++nt) {
        acc2[0][nt] = __builtin_amdgcn_mfma_f32_16x16x32_f16(a0, bf[nt], acc2[0][nt], 0, 0, 0);
        acc2[1][nt] = __builtin_amdgcn_mfma_f32_16x16x32_f16(a1, bf[nt], acc2[1][nt], 0, 0, 0);
      }
    }
  }

  #pragma unroll
  for (int mt = 0; mt < 2; ++mt) {
    #pragma unroll
    for (int nt = 0; nt < 4; ++nt) {
      #pragma unroll
      for (int r = 0; r < 4; ++r) {
        __builtin_nontemporal_store(
            acc2[mt][nt][r],
            &out[((size_t)p * TERM_NUM + t0 + mt * 16 + lg * 4 + r) * HID + w * 64 + nt * 16 + lr]);
      }
    }
  }
}

extern "C" void kernel_launch(void* const* d_in, const int* in_sizes, int n_in,
                              void* d_out, int out_size, void* d_ws, size_t ws_size,
                              hipStream_t stream) {
  const float* term = (const float*)d_in[0];
  const float* pro  = (const float*)d_in[1];
  const int*   lens = (const int*)d_in[2];

  float* out  = (float*)d_out;
  float* attn = out + (size_t)PRO_NUM * TERM_NUM * HID;

  f16x8* fragP = (f16x8*)d_ws;
  f16x8* fragT = fragP + (size_t)PRO_NUM * 64 * 8 * 64;

  k_prep<<<dim3(MAX_LEN / 64, PRO_NUM), 256, 0, stream>>>(pro, fragP, fragT);

  // --- ablation dispatches (garbage results, fully overwritten by the real k_qk below) ---
  k_qk_t<1><<<dim3(PRO_NUM * (TERM_NUM / 32)), 256, 0, stream>>>(term, fragP, lens, attn);
  k_qk_t<2><<<dim3(PRO_NUM * (TERM_NUM / 32)), 256, 0, stream>>>(term, fragP, lens, attn);
  k_qk_t<3><<<dim3(PRO_NUM * (TERM_NUM / 32)), 256, 0, stream>>>(term, fragP, lens, attn);

  // --- real pipeline ---
  k_qk_t<0><<<dim3(PRO_NUM * (TERM_NUM / 32)), 256, 0, stream>>>(term, fragP, lens, attn);
  k_pv<<<dim3(PRO_NUM * (TERM_NUM / 32)), 256, 0, stream>>>(attn, fragT, lens, out);
}

// Round 11
// 135.233 us; speedup vs baseline: 2.6571x; 2.6571x over previous
//
#include <hip/hip_runtime.h>
#include <stdint.h>

#define PRO_NUM 64
#define TERM_NUM 512
#define MAX_LEN 1024
#define HID 256

typedef _Float16 f16x8 __attribute__((ext_vector_type(8)));
typedef float f32x4 __attribute__((ext_vector_type(4)));

__device__ __forceinline__ f16x8 cvt8(const float* __restrict__ s) {
  float4 a = *(const float4*)s;
  float4 b = *(const float4*)(s + 4);
  f16x8 r = {(_Float16)a.x, (_Float16)a.y, (_Float16)a.z, (_Float16)a.w,
             (_Float16)b.x, (_Float16)b.y, (_Float16)b.z, (_Float16)b.w};
  return r;
}

// async global->LDS, 16B per lane; lds base must be wave-uniform (HW adds lane*16)
__device__ __forceinline__ void gll16(const void* g, void* l) {
  __builtin_amdgcn_global_load_lds(
      (const __attribute__((address_space(1))) uint32_t*)g,
      (__attribute__((address_space(3))) uint32_t*)l, 16, 0, 0);
}

// K1: pro f32 -> (a) img: per-(p,64-l-chunk) 32KB swizzled LDS images of pro_h
//                (byte(l,h8) = l*512 + ((h8*16) ^ ((l&7)<<4)), h8 = h/8)
//                (b) fragT: PV B-operand fragments (as before).
__global__ __launch_bounds__(256) void k_prep(const float* __restrict__ pro,
                                              char* __restrict__ img,
                                              f16x8* __restrict__ fragT) {
  __shared__ _Float16 ldsA[64][264];
  const int p = blockIdx.y;
  const int lc = blockIdx.x;
  const int tid = threadIdx.x;

  const float* src = pro + ((size_t)p * MAX_LEN + lc * 64) * HID;
  #pragma unroll
  for (int j = 0; j < 16; ++j) {
    int idx = j * 1024 + tid * 4;
    int l = idx >> 8, h = idx & 255;
    float4 v = *(const float4*)(src + idx);
    ldsA[l][h + 0] = (_Float16)v.x;
    ldsA[l][h + 1] = (_Float16)v.y;
    ldsA[l][h + 2] = (_Float16)v.z;
    ldsA[l][h + 3] = (_Float16)v.w;
  }
  __syncthreads();

  // (a) swizzled image
  {
    char* dst = img + ((size_t)(p * 16 + lc)) * 32768;
    const int h8 = tid & 31;
    const int l0 = tid >> 5;  // 0..7
    #pragma unroll
    for (int j = 0; j < 8; ++j) {
      const int l = j * 8 + l0;
      f16x8 v = *(const f16x8*)&ldsA[l][h8 * 8];
      *(f16x8*)(dst + l * 512 + ((h8 * 16) ^ ((l & 7) << 4))) = v;
    }
  }

  // (b) fragT
  const int w = tid >> 6;
  const int lane = tid & 63;
  const int lr = lane & 15;
  const int lg = lane >> 4;
  #pragma unroll
  for (int hh = 0; hh < 4; ++hh) {
    const int H = w * 4 + hh;
    #pragma unroll
    for (int k2 = 0; k2 < 2; ++k2) {
      const int kc = lc * 2 + k2;
      const int lloc = k2 * 32 + lg * 8;
      f16x8 v;
      #pragma unroll
      for (int i = 0; i < 8; ++i) v[i] = ldsA[lloc + i][H * 16 + lr];
      fragT[((size_t)(p * 16 + H) * 32 + kc) * 64 + lane] = v;
    }
  }
}

// K2 (fused, canonical LDS-staged): block = (p, 32 terms), 4 waves.
// Phase A: 16x 64-l chunks double-buffered via global_load_lds; wave w computes
//   m-tile (w&1) x l-half (w>>1). Softmax -> P into bufA/bufB (f16 swizzled) +
//   scattered NT attn store. Phase C: PV from LDS P + fragT.
__global__ __launch_bounds__(256) void k_fused(
    const float* __restrict__ term, const char* __restrict__ img,
    const f16x8* __restrict__ fragT, const int* __restrict__ lens,
    float* __restrict__ attn, float* __restrict__ out) {
  __shared__ __align__(16) char bufA[32768];  // chunk stage (even) / P rows 0-15
  __shared__ __align__(16) char bufB[32768];  // chunk stage (odd)  / P rows 16-31
  __shared__ float rmx[4][16];
  __shared__ float rsm[4][16];

  const int bid = blockIdx.x;
  const int swz = (bid & 7) * 128 + (bid >> 3);
  const int p = swz >> 4;
  const int t0 = (swz & 15) * 32;

  const int tid = threadIdx.x;
  const int w = tid >> 6;
  const int lane = tid & 63;
  const int lr = lane & 15;
  const int lg = lane >> 4;
  const int len = lens[p];
  const int mw = w & 1;   // m-tile owned by this wave
  const int lh = w >> 1;  // l-half within each chunk

  // A fragments (term rows t0+mw*16+lr)
  f16x8 af[8];
  {
    const float* trow = term + (size_t)(t0 + mw * 16 + lr) * HID + lg * 8;
    #pragma unroll
    for (int kk = 0; kk < 8; ++kk) af[kk] = cvt8(trow + kk * 32);
  }

  f32x4 acc[32];
  #pragma unroll
  for (int i = 0; i < 32; ++i) acc[i] = (f32x4){0.f, 0.f, 0.f, 0.f};

  const char* imgp = img + ((size_t)p * 16) * 32768 + w * 1024 + lane * 16;
  char* stA = bufA + w * 1024;
  char* stB = bufB + w * 1024;

  // prologue: stage chunk 0
  #pragma unroll
  for (int r = 0; r < 8; ++r) gll16(imgp + r * 4096, stA + r * 4096);
  __syncthreads();

  const int swk = (lr & 7) << 4;
  #pragma unroll
  for (int c = 0; c < 16; ++c) {
    // stage next chunk into the other buffer (latency hides under compute)
    if (c < 15) {
      const char* src = imgp + (size_t)(c + 1) * 32768;
      char* dst = (c & 1) ? stA : stB;
      #pragma unroll
      for (int r = 0; r < 8; ++r) gll16(src + r * 4096, dst + r * 4096);
    }
    const char* cur = (c & 1) ? bufB : bufA;
    #pragma unroll
    for (int j = 0; j < 2; ++j) {
      const int lt = lh * 2 + j;
      const char* rowp = cur + (lt * 16 + lr) * 512;
      f16x8 bf[8];
      #pragma unroll
      for (int kk = 0; kk < 8; ++kk)
        bf[kk] = *(const f16x8*)(rowp + ((kk * 64 + lg * 16) ^ swk));
      #pragma unroll
      for (int kk = 0; kk < 8; ++kk)
        acc[c * 2 + j] =
            __builtin_amdgcn_mfma_f32_16x16x32_f16(af[kk], bf[kk], acc[c * 2 + j], 0, 0, 0);
    }
    __syncthreads();  // drains staged loads (vmcnt0) + all waves done with cur
  }

  // ---------------- softmax ----------------
  float rmax[4] = {-INFINITY, -INFINITY, -INFINITY, -INFINITY};
  #pragma unroll
  for (int a = 0; a < 32; ++a) {
    const int l = (a >> 1) * 64 + lh * 32 + (a & 1) * 16 + lr;
    #pragma unroll
    for (int r = 0; r < 4; ++r) {
      float s = (l < len) ? acc[a][r] : -INFINITY;
      acc[a][r] = s;
      rmax[r] = fmaxf(rmax[r], s);
    }
  }
  #pragma unroll
  for (int m = 1; m < 16; m <<= 1) {
    #pragma unroll
    for (int r = 0; r < 4; ++r) rmax[r] = fmaxf(rmax[r], __shfl_xor(rmax[r], m));
  }
  if (lr == 0) {
    #pragma unroll
    for (int r = 0; r < 4; ++r) rmx[w][lg * 4 + r] = rmax[r];
  }
  __syncthreads();
  float fm[4];
  #pragma unroll
  for (int r = 0; r < 4; ++r) {
    const int rl = lg * 4 + r;
    fm[r] = fmaxf(rmx[mw][rl], rmx[2 + mw][rl]);
  }
  float rsum[4] = {0.f, 0.f, 0.f, 0.f};
  #pragma unroll
  for (int a = 0; a < 32; ++a) {
    #pragma unroll
    for (int r = 0; r < 4; ++r) {
      float e = __expf(acc[a][r] - fm[r]);  // masked -> 0
      acc[a][r] = e;
      rsum[r] += e;
    }
  }
  #pragma unroll
  for (int m = 1; m < 16; m <<= 1) {
    #pragma unroll
    for (int r = 0; r < 4; ++r) rsum[r] += __shfl_xor(rsum[r], m);
  }
  if (lr == 0) {
    #pragma unroll
    for (int r = 0; r < 4; ++r) rsm[w][lg * 4 + r] = rsum[r];
  }
  __syncthreads();
  float inv[4];
  #pragma unroll
  for (int r = 0; r < 4; ++r) {
    const int rl = lg * 4 + r;
    inv[r] = 1.0f / (rsm[mw][rl] + rsm[2 + mw][rl]);
  }

  // P -> LDS (f16, col ^ ((row&7)<<3)) in bufA (rows 0-15) / bufB (rows 16-31),
  // fused with scattered NT f32 attn store.
  {
    _Float16* pb = (_Float16*)(mw ? bufB : bufA);
    #pragma unroll
    for (int r = 0; r < 4; ++r) {
      const int rl = lg * 4 + r;
      const int sw = (rl & 7) << 3;
      float* arow = attn + ((size_t)(p * TERM_NUM + t0 + mw * 16 + rl)) * MAX_LEN;
      #pragma unroll
      for (int a = 0; a < 32; ++a) {
        const int l = (a >> 1) * 64 + lh * 32 + (a & 1) * 16 + lr;
        const float v = acc[a][r] * inv[r];
        pb[rl * 1024 + (l ^ sw)] = (_Float16)v;
        __builtin_nontemporal_store(v, &arow[l]);
      }
    }
  }
  __syncthreads();

  // ---------------- Phase C: out = P @ pro ----------------
  f32x4 acc2[2][4];
  #pragma unroll
  for (int mt = 0; mt < 2; ++mt)
    #pragma unroll
    for (int nt = 0; nt < 4; ++nt) acc2[mt][nt] = (f32x4){0.f, 0.f, 0.f, 0.f};

  const _Float16* pa = (const _Float16*)bufA;
  const _Float16* pbb = (const _Float16*)bufB;
  const f16x8* btw = fragT + ((size_t)(p * 16 + w * 4) * 32) * 64 + lane;
  const int kcmax = (len + 31) >> 5;
  const int swp = (lr & 7) << 3;

  #pragma unroll 4
  for (int kc = 0; kc < kcmax; ++kc) {
    const int cidx = ((kc * 32 + lg * 8) ^ swp) + lr * 1024;
    f16x8 bf[4];
    #pragma unroll
    for (int nt = 0; nt < 4; ++nt) bf[nt] = btw[(nt * 32 + kc) * 64];
    f16x8 a0 = *(const f16x8*)&pa[cidx];
    f16x8 a1 = *(const f16x8*)&pbb[cidx];
    #pragma unroll
    for (int nt = 0; nt < 4; ++nt) {
      acc2[0][nt] = __builtin_amdgcn_mfma_f32_16x16x32_f16(a0, bf[nt], acc2[0][nt], 0, 0, 0);
      acc2[1][nt] = __builtin_amdgcn_mfma_f32_16x16x32_f16(a1, bf[nt], acc2[1][nt], 0, 0, 0);
    }
  }

  #pragma unroll
  for (int mt = 0; mt < 2; ++mt) {
    #pragma unroll
    for (int nt = 0; nt < 4; ++nt) {
      #pragma unroll
      for (int r = 0; r < 4; ++r) {
        __builtin_nontemporal_store(
            acc2[mt][nt][r],
            &out[((size_t)p * TERM_NUM + t0 + mt * 16 + lg * 4 + r) * HID + w * 64 + nt * 16 + lr]);
      }
    }
  }
}

extern "C" void kernel_launch(void* const* d_in, const int* in_sizes, int n_in,
                              void* d_out, int out_size, void* d_ws, size_t ws_size,
                              hipStream_t stream) {
  const float* term = (const float*)d_in[0];
  const float* pro  = (const float*)d_in[1];
  const int*   lens = (const int*)d_in[2];

  float* out  = (float*)d_out;
  float* attn = out + (size_t)PRO_NUM * TERM_NUM * HID;

  char*  img   = (char*)d_ws;                                    // 33.55 MB
  f16x8* fragT = (f16x8*)(img + (size_t)PRO_NUM * 16 * 32768);   // 33.55 MB

  k_prep<<<dim3(16, PRO_NUM), 256, 0, stream>>>(pro, img, fragT);
  k_fused<<<dim3(PRO_NUM * (TERM_NUM / 32)), 256, 0, stream>>>(term, img, fragT, lens, attn, out);
}

// Round 12
// 132.033 us; speedup vs baseline: 2.7215x; 1.0242x over previous
//
#include <hip/hip_runtime.h>
#include <stdint.h>

#define PRO_NUM 64
#define TERM_NUM 512
#define MAX_LEN 1024
#define HID 256

typedef _Float16 f16x8 __attribute__((ext_vector_type(8)));
typedef float f32x4 __attribute__((ext_vector_type(4)));

__device__ __forceinline__ f16x8 cvt8(const float* __restrict__ s) {
  float4 a = *(const float4*)s;
  float4 b = *(const float4*)(s + 4);
  f16x8 r = {(_Float16)a.x, (_Float16)a.y, (_Float16)a.z, (_Float16)a.w,
             (_Float16)b.x, (_Float16)b.y, (_Float16)b.z, (_Float16)b.w};
  return r;
}

// async global->LDS, 16B per lane; lds base must be wave-uniform (HW adds lane*16)
__device__ __forceinline__ void gll16(const void* g, void* l) {
  __builtin_amdgcn_global_load_lds(
      (const __attribute__((address_space(1))) uint32_t*)g,
      (__attribute__((address_space(3))) uint32_t*)l, 16, 0, 0);
}

// K1: pro f32 -> (a) img: per-(p,64-l-chunk) 32KB swizzled LDS images of pro_h
//                (byte(l,h8) = l*512 + ((h8*16) ^ ((l&7)<<4)), h8 = h/8)
//                (b) fragT: PV B-operand fragments.
__global__ __launch_bounds__(256) void k_prep(const float* __restrict__ pro,
                                              char* __restrict__ img,
                                              f16x8* __restrict__ fragT) {
  __shared__ _Float16 ldsA[64][264];
  const int p = blockIdx.y;
  const int lc = blockIdx.x;
  const int tid = threadIdx.x;

  const float* src = pro + ((size_t)p * MAX_LEN + lc * 64) * HID;
  #pragma unroll
  for (int j = 0; j < 16; ++j) {
    int idx = j * 1024 + tid * 4;
    int l = idx >> 8, h = idx & 255;
    float4 v = *(const float4*)(src + idx);
    ldsA[l][h + 0] = (_Float16)v.x;
    ldsA[l][h + 1] = (_Float16)v.y;
    ldsA[l][h + 2] = (_Float16)v.z;
    ldsA[l][h + 3] = (_Float16)v.w;
  }
  __syncthreads();

  // (a) swizzled image
  {
    char* dst = img + ((size_t)(p * 16 + lc)) * 32768;
    const int h8 = tid & 31;
    const int l0 = tid >> 5;  // 0..7
    #pragma unroll
    for (int j = 0; j < 8; ++j) {
      const int l = j * 8 + l0;
      f16x8 v = *(const f16x8*)&ldsA[l][h8 * 8];
      *(f16x8*)(dst + l * 512 + ((h8 * 16) ^ ((l & 7) << 4))) = v;
    }
  }

  // (b) fragT
  const int w = tid >> 6;
  const int lane = tid & 63;
  const int lr = lane & 15;
  const int lg = lane >> 4;
  #pragma unroll
  for (int hh = 0; hh < 4; ++hh) {
    const int H = w * 4 + hh;
    #pragma unroll
    for (int k2 = 0; k2 < 2; ++k2) {
      const int kc = lc * 2 + k2;
      const int lloc = k2 * 32 + lg * 8;
      f16x8 v;
      #pragma unroll
      for (int i = 0; i < 8; ++i) v[i] = ldsA[lloc + i][H * 16 + lr];
      fragT[((size_t)(p * 16 + H) * 32 + kc) * 64 + lane] = v;
    }
  }
}

// K2 (fused): block = (p, 32 terms), 4 waves. Phase A: len-clipped chunk loop,
// double-buffered global_load_lds. Softmax -> P to LDS (f16 swizzled). Phase C: PV
// from LDS P + fragT. Finally: coalesced full-line NT attn writeback from LDS P.
__global__ __launch_bounds__(256) void k_fused(
    const float* __restrict__ term, const char* __restrict__ img,
    const f16x8* __restrict__ fragT, const int* __restrict__ lens,
    float* __restrict__ attn, float* __restrict__ out) {
  __shared__ __align__(16) char bufA[32768];  // chunk stage (even) / P rows 0-15
  __shared__ __align__(16) char bufB[32768];  // chunk stage (odd)  / P rows 16-31
  __shared__ float rmx[4][16];
  __shared__ float rsm[4][16];

  const int bid = blockIdx.x;
  const int swz = (bid & 7) * 128 + (bid >> 3);
  const int p = swz >> 4;
  const int t0 = (swz & 15) * 32;

  const int tid = threadIdx.x;
  const int w = tid >> 6;
  const int lane = tid & 63;
  const int lr = lane & 15;
  const int lg = lane >> 4;
  const int len = lens[p];
  const int mw = w & 1;   // m-tile owned by this wave
  const int lh = w >> 1;  // l-half within each chunk
  const int nchunks = (len + 63) >> 6;  // 1..16, wave-uniform

  // A fragments (term rows t0+mw*16+lr)
  f16x8 af[8];
  {
    const float* trow = term + (size_t)(t0 + mw * 16 + lr) * HID + lg * 8;
    #pragma unroll
    for (int kk = 0; kk < 8; ++kk) af[kk] = cvt8(trow + kk * 32);
  }

  f32x4 acc[32];
  #pragma unroll
  for (int i = 0; i < 32; ++i) acc[i] = (f32x4){0.f, 0.f, 0.f, 0.f};

  const char* imgp = img + ((size_t)p * 16) * 32768 + w * 1024 + lane * 16;
  char* stA = bufA + w * 1024;
  char* stB = bufB + w * 1024;

  // prologue: stage chunk 0 (len >= 1 always)
  #pragma unroll
  for (int r = 0; r < 8; ++r) gll16(imgp + r * 4096, stA + r * 4096);
  __syncthreads();

  const int swk = (lr & 7) << 4;
  #pragma unroll
  for (int c = 0; c < 16; ++c) {
    if (c + 1 < nchunks) {  // stage next live chunk
      const char* src = imgp + (size_t)(c + 1) * 32768;
      char* dst = (c & 1) ? stA : stB;
      #pragma unroll
      for (int r = 0; r < 8; ++r) gll16(src + r * 4096, dst + r * 4096);
    }
    if (c < nchunks) {  // compute live chunk (wave-uniform)
      const char* cur = (c & 1) ? bufB : bufA;
      #pragma unroll
      for (int j = 0; j < 2; ++j) {
        const int lt = lh * 2 + j;
        const char* rowp = cur + (lt * 16 + lr) * 512;
        f16x8 bf[8];
        #pragma unroll
        for (int kk = 0; kk < 8; ++kk)
          bf[kk] = *(const f16x8*)(rowp + ((kk * 64 + lg * 16) ^ swk));
        #pragma unroll
        for (int kk = 0; kk < 8; ++kk)
          acc[c * 2 + j] =
              __builtin_amdgcn_mfma_f32_16x16x32_f16(af[kk], bf[kk], acc[c * 2 + j], 0, 0, 0);
      }
    }
    __syncthreads();  // uniform barrier every iteration
  }

  // ---------------- softmax ----------------
  float rmax[4] = {-INFINITY, -INFINITY, -INFINITY, -INFINITY};
  #pragma unroll
  for (int a = 0; a < 32; ++a) {
    const int l = (a >> 1) * 64 + lh * 32 + (a & 1) * 16 + lr;
    #pragma unroll
    for (int r = 0; r < 4; ++r) {
      float s = (l < len) ? acc[a][r] : -INFINITY;
      acc[a][r] = s;
      rmax[r] = fmaxf(rmax[r], s);
    }
  }
  #pragma unroll
  for (int m = 1; m < 16; m <<= 1) {
    #pragma unroll
    for (int r = 0; r < 4; ++r) rmax[r] = fmaxf(rmax[r], __shfl_xor(rmax[r], m));
  }
  if (lr == 0) {
    #pragma unroll
    for (int r = 0; r < 4; ++r) rmx[w][lg * 4 + r] = rmax[r];
  }
  __syncthreads();
  float fm[4];
  #pragma unroll
  for (int r = 0; r < 4; ++r) {
    const int rl = lg * 4 + r;
    fm[r] = fmaxf(rmx[mw][rl], rmx[2 + mw][rl]);
  }
  float rsum[4] = {0.f, 0.f, 0.f, 0.f};
  #pragma unroll
  for (int a = 0; a < 32; ++a) {
    #pragma unroll
    for (int r = 0; r < 4; ++r) {
      float e = __expf(acc[a][r] - fm[r]);  // masked -> 0
      acc[a][r] = e;
      rsum[r] += e;
    }
  }
  #pragma unroll
  for (int m = 1; m < 16; m <<= 1) {
    #pragma unroll
    for (int r = 0; r < 4; ++r) rsum[r] += __shfl_xor(rsum[r], m);
  }
  if (lr == 0) {
    #pragma unroll
    for (int r = 0; r < 4; ++r) rsm[w][lg * 4 + r] = rsum[r];
  }
  __syncthreads();
  float inv[4];
  #pragma unroll
  for (int r = 0; r < 4; ++r) {
    const int rl = lg * 4 + r;
    inv[r] = 1.0f / (rsm[mw][rl] + rsm[2 + mw][rl]);
  }

  // P -> LDS only (f16, col ^ ((row&7)<<3)); bufA rows 0-15, bufB rows 16-31
  {
    _Float16* pb = (_Float16*)(mw ? bufB : bufA);
    #pragma unroll
    for (int r = 0; r < 4; ++r) {
      const int rl = lg * 4 + r;
      const int sw = (rl & 7) << 3;
      #pragma unroll
      for (int a = 0; a < 32; ++a) {
        const int l = (a >> 1) * 64 + lh * 32 + (a & 1) * 16 + lr;
        pb[rl * 1024 + (l ^ sw)] = (_Float16)(acc[a][r] * inv[r]);
      }
    }
  }
  __syncthreads();

  // ---------------- Phase C: out = P @ pro ----------------
  f32x4 acc2[2][4];
  #pragma unroll
  for (int mt = 0; mt < 2; ++mt)
    #pragma unroll
    for (int nt = 0; nt < 4; ++nt) acc2[mt][nt] = (f32x4){0.f, 0.f, 0.f, 0.f};

  const _Float16* pa = (const _Float16*)bufA;
  const _Float16* pbb = (const _Float16*)bufB;
  const f16x8* btw = fragT + ((size_t)(p * 16 + w * 4) * 32) * 64 + lane;
  const int kcmax = (len + 31) >> 5;
  const int swp = (lr & 7) << 3;

  #pragma unroll 4
  for (int kc = 0; kc < kcmax; ++kc) {
    const int cidx = ((kc * 32 + lg * 8) ^ swp) + lr * 1024;
    f16x8 bf[4];
    #pragma unroll
    for (int nt = 0; nt < 4; ++nt) bf[nt] = btw[(nt * 32 + kc) * 64];
    f16x8 a0 = *(const f16x8*)&pa[cidx];
    f16x8 a1 = *(const f16x8*)&pbb[cidx];
    #pragma unroll
    for (int nt = 0; nt < 4; ++nt) {
      acc2[0][nt] = __builtin_amdgcn_mfma_f32_16x16x32_f16(a0, bf[nt], acc2[0][nt], 0, 0, 0);
      acc2[1][nt] = __builtin_amdgcn_mfma_f32_16x16x32_f16(a1, bf[nt], acc2[1][nt], 0, 0, 0);
    }
  }

  #pragma unroll
  for (int mt = 0; mt < 2; ++mt) {
    #pragma unroll
    for (int nt = 0; nt < 4; ++nt) {
      #pragma unroll
      for (int r = 0; r < 4; ++r) {
        __builtin_nontemporal_store(
            acc2[mt][nt][r],
            &out[((size_t)p * TERM_NUM + t0 + mt * 16 + lg * 4 + r) * HID + w * 64 + nt * 16 + lr]);
      }
    }
  }

  // ---------------- coalesced attn writeback (full 128B lines, NT) ----------------
  // thread t: row = t>>3 (0..31), cols (t&7)*8 + j*64; 8-thread groups write 256B runs
  {
    const int row = tid >> 3;
    const int rl = row & 15;
    const int sw = (rl & 7) << 3;
    const _Float16* pb = (const _Float16*)((row < 16) ? bufA : bufB);
    float* arow = attn + ((size_t)(p * TERM_NUM + t0 + row)) * MAX_LEN;
    const int c0 = (tid & 7) * 8;
    #pragma unroll
    for (int j = 0; j < 16; ++j) {
      const int l0 = c0 + j * 64;
      f16x8 v = *(const f16x8*)&pb[rl * 1024 + (l0 ^ sw)];
      f32x4 o0 = {(float)v[0], (float)v[1], (float)v[2], (float)v[3]};
      f32x4 o1 = {(float)v[4], (float)v[5], (float)v[6], (float)v[7]};
      __builtin_nontemporal_store(o0, (f32x4*)(arow + l0));
      __builtin_nontemporal_store(o1, (f32x4*)(arow + l0 + 4));
    }
  }
}

extern "C" void kernel_launch(void* const* d_in, const int* in_sizes, int n_in,
                              void* d_out, int out_size, void* d_ws, size_t ws_size,
                              hipStream_t stream) {
  const float* term = (const float*)d_in[0];
  const float* pro  = (const float*)d_in[1];
  const int*   lens = (const int*)d_in[2];

  float* out  = (float*)d_out;
  float* attn = out + (size_t)PRO_NUM * TERM_NUM * HID;

  char*  img   = (char*)d_ws;                                    // 33.55 MB
  f16x8* fragT = (f16x8*)(img + (size_t)PRO_NUM * 16 * 32768);   // 33.55 MB

  k_prep<<<dim3(16, PRO_NUM), 256, 0, stream>>>(pro, img, fragT);
  k_fused<<<dim3(PRO_NUM * (TERM_NUM / 32)), 256, 0, stream>>>(term, img, fragT, lens, attn, out);
}